// Round 1
// baseline (546.552 us; speedup 1.0000x reference)
//
#include <hip/hip_runtime.h>

#define LR_C 0.01f
#define NB 8
#define NTOK 1024
#define DD 256

// DPP-based butterfly add within 16-lane groups (all VALU, no LDS pipe):
//   0xB1 = quad_perm [1,0,3,2]  (xor 1)
//   0x4E = quad_perm [2,3,0,1]  (xor 2)
//   0x141 = row_half_mirror     (pairs quads within 8)
//   0x140 = row_mirror          (pairs 8-groups within 16)
#define DPP_ADD(x, ctrl) \
    ((x) + __int_as_float(__builtin_amdgcn_update_dpp( \
        0, __float_as_int(x), (ctrl), 0xF, 0xF, true)))

// ---------------------------------------------------------------------------
// GEMM: C[m][n] = sum_k A[m][k] * B[n][k]   (A: Mx256, B: 256x256, C: Mx256)
// 128x128 tile, BK=8, 256 threads, 8x8 per thread.
// ---------------------------------------------------------------------------
#define GBM 128
#define GBN 128
#define GBK 8

__global__ __launch_bounds__(256) void gemm_abt_kernel(
    const float* __restrict__ A, const float* __restrict__ B,
    float* __restrict__ C)
{
    __shared__ float As[GBK][GBM];
    __shared__ float Bs[GBK][GBN];
    const int t  = threadIdx.x;
    const int bm = blockIdx.x;
    const int bn = blockIdx.y;

    const int lrow = t >> 1;          // 0..127 tile row to load
    const int lkc  = (t & 1) * 4;     // 0 or 4 within BK
    const int tx   = t & 15;          // output col group
    const int ty   = t >> 4;          // output row group

    float acc[8][8];
    #pragma unroll
    for (int i = 0; i < 8; ++i)
        #pragma unroll
        for (int j = 0; j < 8; ++j) acc[i][j] = 0.f;

    const float* Arow = A + (size_t)(bm * GBM + lrow) * DD + lkc;
    const float* Brow = B + (size_t)(bn * GBN + lrow) * DD + lkc;

    for (int k0 = 0; k0 < DD; k0 += GBK) {
        float4 av = *reinterpret_cast<const float4*>(Arow + k0);
        float4 bv = *reinterpret_cast<const float4*>(Brow + k0);
        __syncthreads();
        As[lkc + 0][lrow] = av.x; As[lkc + 1][lrow] = av.y;
        As[lkc + 2][lrow] = av.z; As[lkc + 3][lrow] = av.w;
        Bs[lkc + 0][lrow] = bv.x; Bs[lkc + 1][lrow] = bv.y;
        Bs[lkc + 2][lrow] = bv.z; Bs[lkc + 3][lrow] = bv.w;
        __syncthreads();
        #pragma unroll
        for (int k = 0; k < GBK; ++k) {
            float a[8], b[8];
            *reinterpret_cast<float4*>(&a[0]) =
                *reinterpret_cast<const float4*>(&As[k][ty * 8]);
            *reinterpret_cast<float4*>(&a[4]) =
                *reinterpret_cast<const float4*>(&As[k][ty * 8 + 4]);
            *reinterpret_cast<float4*>(&b[0]) =
                *reinterpret_cast<const float4*>(&Bs[k][tx * 8]);
            *reinterpret_cast<float4*>(&b[4]) =
                *reinterpret_cast<const float4*>(&Bs[k][tx * 8 + 4]);
            #pragma unroll
            for (int i = 0; i < 8; ++i)
                #pragma unroll
                for (int j = 0; j < 8; ++j)
                    acc[i][j] += a[i] * b[j];
        }
    }
    #pragma unroll
    for (int i = 0; i < 8; ++i) {
        float* cp = C + (size_t)(bm * GBM + ty * 8 + i) * DD + bn * GBN + tx * 8;
        *reinterpret_cast<float4*>(cp) =
            make_float4(acc[i][0], acc[i][1], acc[i][2], acc[i][3]);
        *reinterpret_cast<float4*>(cp + 4) =
            make_float4(acc[i][4], acc[i][5], acc[i][6], acc[i][7]);
    }
}

// ---------------------------------------------------------------------------
// Sequential delta-rule scan. Grid: 512 blocks x 64 threads.
// Block = (batch b, 4 theta rows). 16 lanes per row; lane owns 16 columns.
// Per token: dot(16 FMA) -> DPP butterfly reduce(16 lanes) -> err -> update.
// h/tgt for t+1 register-prefetched during token t.
// ---------------------------------------------------------------------------
__global__ __launch_bounds__(64) void theta_scan_kernel(
    const float* __restrict__ H, const float* __restrict__ Tgt,
    const float* __restrict__ theta0, float* __restrict__ Pred)
{
    const int wg   = blockIdx.x;
    const int b    = wg >> 6;            // 8 batches
    const int rb   = wg & 63;            // 64 row-blocks of 4 rows
    const int lane = threadIdx.x & 15;
    const int row  = rb * 4 + (threadIdx.x >> 4);
    const int col0 = lane * 16;

    float4 th0, th1, th2, th3;
    {
        const float4* tp =
            reinterpret_cast<const float4*>(theta0 + row * DD + col0);
        th0 = tp[0]; th1 = tp[1]; th2 = tp[2]; th3 = tp[3];
    }

    const float* Hb = H   + (size_t)b * NTOK * DD + col0;
    const float* Tb = Tgt + (size_t)b * NTOK * DD + row;
    float*       Pb = Pred + (size_t)b * NTOK * DD + row;

    float4 h0, h1, h2, h3; float tg;
    {
        const float4* hp = reinterpret_cast<const float4*>(Hb);
        h0 = hp[0]; h1 = hp[1]; h2 = hp[2]; h3 = hp[3];
        tg = Tb[0];
    }

    for (int t = 0; t < NTOK; ++t) {
        // prefetch next token (uniform branch-free clamp; tail re-reads t=1023)
        const int tn = (t + 1 < NTOK) ? (t + 1) : (NTOK - 1);
        const float4* hq = reinterpret_cast<const float4*>(Hb + (size_t)tn * DD);
        float4 n0 = hq[0], n1 = hq[1], n2 = hq[2], n3 = hq[3];
        float tgn = Tb[(size_t)tn * DD];

        // dot partial: 16 FMAs, 4 accumulators
        float s0 = th0.x * h0.x + th0.y * h0.y + th0.z * h0.z + th0.w * h0.w;
        float s1 = th1.x * h1.x + th1.y * h1.y + th1.z * h1.z + th1.w * h1.w;
        float s2 = th2.x * h2.x + th2.y * h2.y + th2.z * h2.z + th2.w * h2.w;
        float s3 = th3.x * h3.x + th3.y * h3.y + th3.z * h3.z + th3.w * h3.w;
        float s = (s0 + s1) + (s2 + s3);

        // 16-lane butterfly, pure DPP
        s = DPP_ADD(s, 0xB1);
        s = DPP_ADD(s, 0x4E);
        s = DPP_ADD(s, 0x141);
        s = DPP_ADD(s, 0x140);

        if (lane == 0) Pb[(size_t)t * DD] = s;

        const float e = LR_C * (tg - s);
        th0.x += e * h0.x; th0.y += e * h0.y; th0.z += e * h0.z; th0.w += e * h0.w;
        th1.x += e * h1.x; th1.y += e * h1.y; th1.z += e * h1.z; th1.w += e * h1.w;
        th2.x += e * h2.x; th2.y += e * h2.y; th2.z += e * h2.z; th2.w += e * h2.w;
        th3.x += e * h3.x; th3.y += e * h3.y; th3.z += e * h3.z; th3.w += e * h3.w;

        h0 = n0; h1 = n1; h2 = n2; h3 = n3; tg = tgn;
    }
}

// ---------------------------------------------------------------------------
extern "C" void kernel_launch(void* const* d_in, const int* in_sizes, int n_in,
                              void* d_out, int out_size, void* d_ws, size_t ws_size,
                              hipStream_t stream) {
    const float* seq    = (const float*)d_in[0];
    const float* tgt    = (const float*)d_in[1];
    const float* theta0 = (const float*)d_in[2];
    const float* W_e    = (const float*)d_in[3];
    const float* W_o    = (const float*)d_in[4];
    float* out = (float*)d_out;

    float* Hbuf = (float*)d_ws;                         // 8192*256 f32 = 8 MB
    float* Pbuf = Hbuf + (size_t)NB * NTOK * DD;        // 8 MB more

    dim3 ggrid(NB * NTOK / GBM, DD / GBN);              // (64, 2)

    // H = X @ W_e^T
    gemm_abt_kernel<<<ggrid, 256, 0, stream>>>(seq, W_e, Hbuf);
    // sequential delta-rule scan -> PRED
    theta_scan_kernel<<<512, 64, 0, stream>>>(Hbuf, tgt, theta0, Pbuf);
    // OUT = PRED @ W_o^T
    gemm_abt_kernel<<<ggrid, 256, 0, stream>>>(Pbuf, W_o, out);
}

// Round 3
// 228.487 us; speedup vs baseline: 2.3920x; 2.3920x over previous
//
#include <hip/hip_runtime.h>

#define LR_C 0.01f
#define NB 8
#define NTOK 1024
#define DD 256

// DPP helper: s += dpp_move(s, ctrl) with bound_ctrl=true (invalid lanes -> 0)
#define DPP_ADD(x, ctrl) \
    ((x) + __int_as_float(__builtin_amdgcn_update_dpp( \
        0, __float_as_int(x), (ctrl), 0xF, 0xF, true)))

// ---------------------------------------------------------------------------
// GEMM: C[m][n] = sum_k A[m][k] * B[n][k]   (A: Mx256, B: 256x256, C: Mx256)
// 128x64 tile, BK=16, 256 threads, 8x4 per thread, reg double-buffered loads.
// grid (8192/128, 256/64) = (64,4) = 256 blocks = 1/CU.
// ---------------------------------------------------------------------------
#define TBM 128
#define TBN 64
#define TBK 16

__global__ __launch_bounds__(256) void gemm_abt_kernel(
    const float* __restrict__ A, const float* __restrict__ B,
    float* __restrict__ C)
{
    __shared__ float As[TBK][TBM + 4];
    __shared__ float Bs[TBK][TBN + 4];
    const int t    = threadIdx.x;
    const int arow = t >> 1, ak = (t & 1) * 8;   // A: 128 rows x 16 k
    const int brow = t >> 2, bk = (t & 3) * 4;   // B: 64 rows x 16 k
    const int tx   = t & 15, ty = t >> 4;        // out: ty*8 rows, tx*4 cols

    const float* Ap = A + (size_t)(blockIdx.x * TBM + arow) * DD + ak;
    const float* Bp = B + (size_t)(blockIdx.y * TBN + brow) * DD + bk;

    float4 acc[8];
    #pragma unroll
    for (int i = 0; i < 8; ++i) acc[i] = make_float4(0.f, 0.f, 0.f, 0.f);

    // prologue load (tile 0)
    float4 a0 = *reinterpret_cast<const float4*>(Ap);
    float4 a1 = *reinterpret_cast<const float4*>(Ap + 4);
    float4 b0 = *reinterpret_cast<const float4*>(Bp);

    for (int k0 = 0; k0 < DD; k0 += TBK) {
        __syncthreads();
        As[ak + 0][arow] = a0.x; As[ak + 1][arow] = a0.y;
        As[ak + 2][arow] = a0.z; As[ak + 3][arow] = a0.w;
        As[ak + 4][arow] = a1.x; As[ak + 5][arow] = a1.y;
        As[ak + 6][arow] = a1.z; As[ak + 7][arow] = a1.w;
        Bs[bk + 0][brow] = b0.x; Bs[bk + 1][brow] = b0.y;
        Bs[bk + 2][brow] = b0.z; Bs[bk + 3][brow] = b0.w;
        __syncthreads();
        if (k0 + TBK < DD) {   // prefetch next tile into regs (hidden by compute)
            a0 = *reinterpret_cast<const float4*>(Ap + k0 + TBK);
            a1 = *reinterpret_cast<const float4*>(Ap + k0 + TBK + 4);
            b0 = *reinterpret_cast<const float4*>(Bp + k0 + TBK);
        }
        #pragma unroll
        for (int k = 0; k < TBK; ++k) {
            float4 av0 = *reinterpret_cast<const float4*>(&As[k][ty * 8]);
            float4 av1 = *reinterpret_cast<const float4*>(&As[k][ty * 8 + 4]);
            float4 bv  = *reinterpret_cast<const float4*>(&Bs[k][tx * 4]);
            float ar[8] = {av0.x, av0.y, av0.z, av0.w, av1.x, av1.y, av1.z, av1.w};
            #pragma unroll
            for (int i = 0; i < 8; ++i) {
                acc[i].x = fmaf(ar[i], bv.x, acc[i].x);
                acc[i].y = fmaf(ar[i], bv.y, acc[i].y);
                acc[i].z = fmaf(ar[i], bv.z, acc[i].z);
                acc[i].w = fmaf(ar[i], bv.w, acc[i].w);
            }
        }
    }
    #pragma unroll
    for (int i = 0; i < 8; ++i) {
        float* cp = C + (size_t)(blockIdx.x * TBM + ty * 8 + i) * DD
                      + blockIdx.y * TBN + tx * 4;
        *reinterpret_cast<float4*>(cp) = acc[i];
    }
}

// ---------------------------------------------------------------------------
// Sequential delta-rule scan. Grid: 2048 blocks x 64 threads (1 wave each).
// Wave = (batch b, theta row). Lane owns 4 columns. 2 waves/SIMD.
// Reduce: 4-step DPP butterfly (16) + row_bcast15 + row_bcast31 + readlane63.
// Depth-8 register prefetch pipeline on h and tgt.
// ---------------------------------------------------------------------------
#define PF 8

__global__ __launch_bounds__(64) void theta_scan_kernel(
    const float* __restrict__ H, const float* __restrict__ Tgt,
    const float* __restrict__ theta0, float* __restrict__ Pred)
{
    const int blk  = blockIdx.x;
    const int b    = blk >> 8;           // 8 batches
    const int row  = blk & 255;          // 256 rows
    const int lane = threadIdx.x;        // 0..63, owns cols lane*4..lane*4+3

    float4 th = *reinterpret_cast<const float4*>(
        theta0 + (size_t)row * DD + lane * 4);

    const float* Hb = H    + (size_t)b * NTOK * DD + lane * 4;
    const float* Tb = Tgt  + (size_t)b * NTOK * DD + row;
    float*       Pb = Pred + (size_t)b * NTOK * DD + row;

    float4 hp[PF]; float tp[PF];
    #pragma unroll
    for (int p = 0; p < PF; ++p) {
        hp[p] = *reinterpret_cast<const float4*>(Hb + (size_t)p * DD);
        tp[p] = Tb[(size_t)p * DD];
    }

    for (int t0 = 0; t0 < NTOK; t0 += PF) {
        float predv = 0.f;   // lane p collects pred for token t0+p
        #pragma unroll
        for (int p = 0; p < PF; ++p) {
            const int t = t0 + p;
            const float4 h  = hp[p];
            const float  tg = tp[p];
            int tn = t + PF; if (tn > NTOK - 1) tn = NTOK - 1;
            hp[p] = *reinterpret_cast<const float4*>(Hb + (size_t)tn * DD);
            tp[p] = Tb[(size_t)tn * DD];

            // partial dot: 4 cols
            float s = th.x * h.x;
            s = fmaf(th.y, h.y, s);
            s = fmaf(th.z, h.z, s);
            s = fmaf(th.w, h.w, s);
            // 16-lane butterfly (all lanes get 16-group sum)
            s = DPP_ADD(s, 0xB1);   // quad_perm xor1
            s = DPP_ADD(s, 0x4E);   // quad_perm xor2
            s = DPP_ADD(s, 0x141);  // row_half_mirror (xor4)
            s = DPP_ADD(s, 0x140);  // row_mirror (xor8)
            // cross 16-groups: total lands in lane 63
            s = DPP_ADD(s, 0x142);  // row_bcast15
            s = DPP_ADD(s, 0x143);  // row_bcast31
            const float stot = __int_as_float(
                __builtin_amdgcn_readlane(__float_as_int(s), 63));

            // stot is wave-uniform: select into lane p (one v_cndmask)
            predv = (lane == p) ? stot : predv;

            const float e = LR_C * (tg - stot);
            th.x = fmaf(e, h.x, th.x);
            th.y = fmaf(e, h.y, th.y);
            th.z = fmaf(e, h.z, th.z);
            th.w = fmaf(e, h.w, th.w);
        }
        if (lane < PF) Pb[(size_t)(t0 + lane) * DD] = predv;
    }
}

// ---------------------------------------------------------------------------
extern "C" void kernel_launch(void* const* d_in, const int* in_sizes, int n_in,
                              void* d_out, int out_size, void* d_ws, size_t ws_size,
                              hipStream_t stream) {
    const float* seq    = (const float*)d_in[0];
    const float* tgt    = (const float*)d_in[1];
    const float* theta0 = (const float*)d_in[2];
    const float* W_e    = (const float*)d_in[3];
    const float* W_o    = (const float*)d_in[4];
    float* out = (float*)d_out;

    float* Hbuf = (float*)d_ws;                      // 8 MB
    float* Pbuf = Hbuf + (size_t)NB * NTOK * DD;     // 8 MB

    dim3 ggrid(NB * NTOK / TBM, DD / TBN);           // (64, 4)

    gemm_abt_kernel<<<ggrid, 256, 0, stream>>>(seq, W_e, Hbuf);
    theta_scan_kernel<<<NB * 256, 64, 0, stream>>>(Hbuf, tgt, theta0, Pbuf);
    gemm_abt_kernel<<<ggrid, 256, 0, stream>>>(Pbuf, W_o, out);
}

// Round 4
// 223.619 us; speedup vs baseline: 2.4441x; 1.0218x over previous
//
#include <hip/hip_runtime.h>

#define LR_C 0.01f
#define NB 8
#define NTOK 1024
#define DD 256
#define CH 8
#define NCHUNK (NTOK / CH)   // 128

// DPP add: s += dpp_move(s, ctrl), bound_ctrl=true
#define DPP_ADD(x, ctrl) \
    ((x) + __int_as_float(__builtin_amdgcn_update_dpp( \
        0, __float_as_int(x), (ctrl), 0xF, 0xF, true)))

// Full 64-lane all-lanes sum: xor1,2 (quad_perm), xor4 (row_half_mirror),
// xor8 (row_mirror), xor16/xor32 via ds_bpermute shuffles.
#define REDUCE_ALL64(s) do { \
    s = DPP_ADD(s, 0xB1); \
    s = DPP_ADD(s, 0x4E); \
    s = DPP_ADD(s, 0x141); \
    s = DPP_ADD(s, 0x140); \
    s += __shfl_xor(s, 16, 64); \
    s += __shfl_xor(s, 32, 64); \
} while (0)

// ---------------------------------------------------------------------------
// GEMM: C[m][n] = sum_k A[m][k]*B[n][k]. 64x64 tile, BK=16, 256 thr, 4x4/thr.
// grid (128,4) = 512 blocks = 2 blocks/CU = 2 waves/SIMD.
// ---------------------------------------------------------------------------
#define TBM 64
#define TBN 64
#define TBK 16

__global__ __launch_bounds__(256) void gemm_abt_kernel(
    const float* __restrict__ A, const float* __restrict__ B,
    float* __restrict__ C)
{
    __shared__ float As[TBK][TBM + 4];
    __shared__ float Bs[TBK][TBN + 4];
    const int t    = threadIdx.x;
    const int lrow = t >> 2, lk = (t & 3) * 4;
    const int tx   = t & 15, ty = t >> 4;

    const float* Ap = A + (size_t)(blockIdx.x * TBM + lrow) * DD + lk;
    const float* Bp = B + (size_t)(blockIdx.y * TBN + lrow) * DD + lk;

    float4 acc[4];
    #pragma unroll
    for (int i = 0; i < 4; ++i) acc[i] = make_float4(0.f, 0.f, 0.f, 0.f);

    float4 a0 = *reinterpret_cast<const float4*>(Ap);
    float4 b0 = *reinterpret_cast<const float4*>(Bp);

    for (int k0 = 0; k0 < DD; k0 += TBK) {
        __syncthreads();
        As[lk + 0][lrow] = a0.x; As[lk + 1][lrow] = a0.y;
        As[lk + 2][lrow] = a0.z; As[lk + 3][lrow] = a0.w;
        Bs[lk + 0][lrow] = b0.x; Bs[lk + 1][lrow] = b0.y;
        Bs[lk + 2][lrow] = b0.z; Bs[lk + 3][lrow] = b0.w;
        __syncthreads();
        if (k0 + TBK < DD) {
            a0 = *reinterpret_cast<const float4*>(Ap + k0 + TBK);
            b0 = *reinterpret_cast<const float4*>(Bp + k0 + TBK);
        }
        #pragma unroll
        for (int k = 0; k < TBK; ++k) {
            float4 av = *reinterpret_cast<const float4*>(&As[k][ty * 4]);
            float4 bv = *reinterpret_cast<const float4*>(&Bs[k][tx * 4]);
            acc[0].x = fmaf(av.x, bv.x, acc[0].x); acc[0].y = fmaf(av.x, bv.y, acc[0].y);
            acc[0].z = fmaf(av.x, bv.z, acc[0].z); acc[0].w = fmaf(av.x, bv.w, acc[0].w);
            acc[1].x = fmaf(av.y, bv.x, acc[1].x); acc[1].y = fmaf(av.y, bv.y, acc[1].y);
            acc[1].z = fmaf(av.y, bv.z, acc[1].z); acc[1].w = fmaf(av.y, bv.w, acc[1].w);
            acc[2].x = fmaf(av.z, bv.x, acc[2].x); acc[2].y = fmaf(av.z, bv.y, acc[2].y);
            acc[2].z = fmaf(av.z, bv.z, acc[2].z); acc[2].w = fmaf(av.z, bv.w, acc[2].w);
            acc[3].x = fmaf(av.w, bv.x, acc[3].x); acc[3].y = fmaf(av.w, bv.y, acc[3].y);
            acc[3].z = fmaf(av.w, bv.z, acc[3].z); acc[3].w = fmaf(av.w, bv.w, acc[3].w);
        }
    }
    #pragma unroll
    for (int i = 0; i < 4; ++i) {
        float* cp = C + (size_t)(blockIdx.x * TBM + ty * 4 + i) * DD
                      + blockIdx.y * TBN + tx * 4;
        *reinterpret_cast<float4*>(cp) = acc[i];
    }
}

// ---------------------------------------------------------------------------
// Per-(batch,chunk) Gram: c_ij = h_i . h_j (full 256-dot) for j<i in chunk of 8.
// 1024 blocks x 64 threads. idx(j,i) = i*(i-1)/2 + j, stored padded to 32.
// ---------------------------------------------------------------------------
__global__ __launch_bounds__(64) void gram_kernel(
    const float* __restrict__ H, float* __restrict__ Gram)
{
    const int blk  = blockIdx.x;              // b*NCHUNK + ch
    const int lane = threadIdx.x;
    const float* Hc = H + (size_t)blk * CH * DD + lane * 4;

    float4 h[CH];
    #pragma unroll
    for (int i = 0; i < CH; ++i)
        h[i] = *reinterpret_cast<const float4*>(Hc + (size_t)i * DD);

    float sel = 0.f;
    #pragma unroll
    for (int i = 1; i < CH; ++i) {
        #pragma unroll
        for (int j = 0; j < i; ++j) {
            float s = h[j].x * h[i].x;
            s = fmaf(h[j].y, h[i].y, s);
            s = fmaf(h[j].z, h[i].z, s);
            s = fmaf(h[j].w, h[i].w, s);
            REDUCE_ALL64(s);
            const int idx = i * (i - 1) / 2 + j;
            sel = (lane == idx) ? s : sel;
        }
    }
    if (lane < 28) Gram[(size_t)blk * 32 + lane] = sel;
}

// ---------------------------------------------------------------------------
// Chunked scan: wave = (batch, theta row). Per 8-token chunk:
//  a_i = theta_T . h_i (8 independent all-lane reduces)
//  p_i = a_i + sum_{j<i} e_j * c_ji ;  e_i = lr*(tg_i - p_i) (pre-scaled)
//  theta += sum_j e_j h_j
// Double-buffered (A/B) register pipeline over chunks, all compile-time idx.
// ---------------------------------------------------------------------------
#define STEP(HC, TC, CC, HN, TN, CN, ch) do { \
    const int nc_ = ((ch) + 1 < NCHUNK) ? (ch) + 1 : NCHUNK - 1; \
    const float* hsrc_ = Hb + (size_t)nc_ * CH * DD; \
    const float* tsrc_ = Tb + (size_t)nc_ * CH * DD; \
    const float* gsrc_ = Gb + nc_ * 32; \
    _Pragma("unroll") \
    for (int i_ = 0; i_ < CH; ++i_) { \
        HN[i_] = *reinterpret_cast<const float4*>(hsrc_ + (size_t)i_ * DD); \
        TN[i_] = LR_C * tsrc_[(size_t)i_ * DD]; \
    } \
    _Pragma("unroll") \
    for (int q_ = 0; q_ < 28; ++q_) CN[q_] = gsrc_[q_]; \
    float a_[CH]; \
    _Pragma("unroll") \
    for (int i_ = 0; i_ < CH; ++i_) { \
        float s_ = HC[i_].x * th.x; \
        s_ = fmaf(HC[i_].y, th.y, s_); \
        s_ = fmaf(HC[i_].z, th.z, s_); \
        s_ = fmaf(HC[i_].w, th.w, s_); \
        REDUCE_ALL64(s_); \
        a_[i_] = s_; \
    } \
    float e_[CH], p_[CH]; \
    _Pragma("unroll") \
    for (int i_ = 0; i_ < CH; ++i_) { \
        float pv_ = a_[i_]; \
        _Pragma("unroll") \
        for (int j_ = 0; j_ < i_; ++j_) \
            pv_ = fmaf(e_[j_], CC[i_ * (i_ - 1) / 2 + j_], pv_); \
        p_[i_] = pv_; \
        e_[i_] = fmaf(-LR_C, pv_, TC[i_]); \
    } \
    _Pragma("unroll") \
    for (int j_ = 0; j_ < CH; ++j_) { \
        th.x = fmaf(e_[j_], HC[j_].x, th.x); \
        th.y = fmaf(e_[j_], HC[j_].y, th.y); \
        th.z = fmaf(e_[j_], HC[j_].z, th.z); \
        th.w = fmaf(e_[j_], HC[j_].w, th.w); \
    } \
    float sel_ = p_[0]; \
    _Pragma("unroll") \
    for (int i_ = 1; i_ < CH; ++i_) sel_ = (lane == i_) ? p_[i_] : sel_; \
    if (lane < CH) Pb[(size_t)((ch) * CH + lane) * DD] = sel_; \
} while (0)

__global__ __launch_bounds__(64) void theta_scan_kernel(
    const float* __restrict__ H, const float* __restrict__ Tgt,
    const float* __restrict__ theta0, const float* __restrict__ Gram,
    float* __restrict__ Pred)
{
    const int blk  = blockIdx.x;
    const int b    = blk >> 8;           // 8 batches
    const int row  = blk & 255;          // 256 rows
    const int lane = threadIdx.x;        // owns cols lane*4 .. lane*4+3

    float4 th = *reinterpret_cast<const float4*>(
        theta0 + (size_t)row * DD + lane * 4);

    const float* Hb = H    + (size_t)b * NTOK * DD + lane * 4;
    const float* Tb = Tgt  + (size_t)b * NTOK * DD + row;
    const float* Gb = Gram + (size_t)b * NCHUNK * 32;
    float*       Pb = Pred + (size_t)b * NTOK * DD + row;

    float4 hA[CH]; float tA[CH], cA[28];
    float4 hB[CH]; float tB[CH], cB[28];

    #pragma unroll
    for (int i = 0; i < CH; ++i) {
        hA[i] = *reinterpret_cast<const float4*>(Hb + (size_t)i * DD);
        tA[i] = LR_C * Tb[(size_t)i * DD];
    }
    #pragma unroll
    for (int q = 0; q < 28; ++q) cA[q] = Gb[q];

    for (int ch = 0; ch < NCHUNK; ch += 2) {
        STEP(hA, tA, cA, hB, tB, cB, ch);
        STEP(hB, tB, cB, hA, tA, cA, ch + 1);
    }
}

// ---------------------------------------------------------------------------
extern "C" void kernel_launch(void* const* d_in, const int* in_sizes, int n_in,
                              void* d_out, int out_size, void* d_ws, size_t ws_size,
                              hipStream_t stream) {
    const float* seq    = (const float*)d_in[0];
    const float* tgt    = (const float*)d_in[1];
    const float* theta0 = (const float*)d_in[2];
    const float* W_e    = (const float*)d_in[3];
    const float* W_o    = (const float*)d_in[4];
    float* out = (float*)d_out;

    float* Hbuf = (float*)d_ws;                      // 8 MB
    float* Pbuf = Hbuf + (size_t)NB * NTOK * DD;     // 8 MB
    // Gram scratch lives in d_out (128 KB); final GEMM overwrites all of d_out.
    float* Cbuf = out;

    dim3 ggrid(NB * NTOK / TBM, DD / TBN);           // (128, 4)

    gemm_abt_kernel<<<ggrid, 256, 0, stream>>>(seq, W_e, Hbuf);
    gram_kernel<<<NB * NCHUNK, 64, 0, stream>>>(Hbuf, Cbuf);
    theta_scan_kernel<<<NB * 256, 64, 0, stream>>>(Hbuf, tgt, theta0, Cbuf, Pbuf);
    gemm_abt_kernel<<<ggrid, 256, 0, stream>>>(Pbuf, W_o, out);
}

// Round 5
// 213.923 us; speedup vs baseline: 2.5549x; 1.0453x over previous
//
#include <hip/hip_runtime.h>

#define LR_C 0.01f
#define NB 8
#define NTOK 1024
#define DD 256
#define CH 8
#define NCHUNK (NTOK / CH)   // 128

// DPP add: s += dpp_move(s, ctrl), bound_ctrl=true
#define DPP_ADD(x, ctrl) \
    ((x) + __int_as_float(__builtin_amdgcn_update_dpp( \
        0, __float_as_int(x), (ctrl), 0xF, 0xF, true)))

// Full 64-lane all-lanes sum.
#define REDUCE_ALL64(s) do { \
    s = DPP_ADD(s, 0xB1); \
    s = DPP_ADD(s, 0x4E); \
    s = DPP_ADD(s, 0x141); \
    s = DPP_ADD(s, 0x140); \
    s += __shfl_xor(s, 16, 64); \
    s += __shfl_xor(s, 32, 64); \
} while (0)

// ---------------------------------------------------------------------------
// GEMM1: C[m][n] = sum_k A[m][k]*B[n][k]. 64x64 tile, BK=16, 256 thr, 4x4/thr.
// ---------------------------------------------------------------------------
#define TBM 64
#define TBN 64
#define TBK 16

__global__ __launch_bounds__(256) void gemm_abt_kernel(
    const float* __restrict__ A, const float* __restrict__ B,
    float* __restrict__ C)
{
    __shared__ float As[TBK][TBM + 4];
    __shared__ float Bs[TBK][TBN + 4];
    const int t    = threadIdx.x;
    const int lrow = t >> 2, lk = (t & 3) * 4;
    const int tx   = t & 15, ty = t >> 4;

    const float* Ap = A + (size_t)(blockIdx.x * TBM + lrow) * DD + lk;
    const float* Bp = B + (size_t)(blockIdx.y * TBN + lrow) * DD + lk;

    float4 acc[4];
    #pragma unroll
    for (int i = 0; i < 4; ++i) acc[i] = make_float4(0.f, 0.f, 0.f, 0.f);

    float4 a0 = *reinterpret_cast<const float4*>(Ap);
    float4 b0 = *reinterpret_cast<const float4*>(Bp);

    for (int k0 = 0; k0 < DD; k0 += TBK) {
        __syncthreads();
        As[lk + 0][lrow] = a0.x; As[lk + 1][lrow] = a0.y;
        As[lk + 2][lrow] = a0.z; As[lk + 3][lrow] = a0.w;
        Bs[lk + 0][lrow] = b0.x; Bs[lk + 1][lrow] = b0.y;
        Bs[lk + 2][lrow] = b0.z; Bs[lk + 3][lrow] = b0.w;
        __syncthreads();
        if (k0 + TBK < DD) {
            a0 = *reinterpret_cast<const float4*>(Ap + k0 + TBK);
            b0 = *reinterpret_cast<const float4*>(Bp + k0 + TBK);
        }
        #pragma unroll
        for (int k = 0; k < TBK; ++k) {
            float4 av = *reinterpret_cast<const float4*>(&As[k][ty * 4]);
            float4 bv = *reinterpret_cast<const float4*>(&Bs[k][tx * 4]);
            acc[0].x = fmaf(av.x, bv.x, acc[0].x); acc[0].y = fmaf(av.x, bv.y, acc[0].y);
            acc[0].z = fmaf(av.x, bv.z, acc[0].z); acc[0].w = fmaf(av.x, bv.w, acc[0].w);
            acc[1].x = fmaf(av.y, bv.x, acc[1].x); acc[1].y = fmaf(av.y, bv.y, acc[1].y);
            acc[1].z = fmaf(av.y, bv.z, acc[1].z); acc[1].w = fmaf(av.y, bv.w, acc[1].w);
            acc[2].x = fmaf(av.z, bv.x, acc[2].x); acc[2].y = fmaf(av.z, bv.y, acc[2].y);
            acc[2].z = fmaf(av.z, bv.z, acc[2].z); acc[2].w = fmaf(av.z, bv.w, acc[2].w);
            acc[3].x = fmaf(av.w, bv.x, acc[3].x); acc[3].y = fmaf(av.w, bv.y, acc[3].y);
            acc[3].z = fmaf(av.w, bv.z, acc[3].z); acc[3].w = fmaf(av.w, bv.w, acc[3].w);
        }
    }
    #pragma unroll
    for (int i = 0; i < 4; ++i) {
        float* cp = C + (size_t)(blockIdx.x * TBM + ty * 4 + i) * DD
                      + blockIdx.y * TBN + tx * 4;
        *reinterpret_cast<float4*>(cp) = acc[i];
    }
}

// ---------------------------------------------------------------------------
// GEMM2: C[b*1024+t][n] = sum_k PT[b][k][t] * B[n][k].  PT is [NB][DD][NTOK].
// A-tile loads are contiguous in t (coalesced), stored to As[k][m] directly.
// ---------------------------------------------------------------------------
__global__ __launch_bounds__(256) void gemm_pt_kernel(
    const float* __restrict__ PT, const float* __restrict__ B,
    float* __restrict__ C)
{
    __shared__ float As[TBK][TBM + 4];
    __shared__ float Bs[TBK][TBN + 4];
    const int t  = threadIdx.x;
    const int mb = blockIdx.x;               // 0..127
    const int b  = mb >> 4;                  // 16 m-tiles per batch
    const int t0 = (mb & 15) * TBM;
    const int bn = blockIdx.y;

    const int akrow = t >> 4, amcol = (t & 15) * 4;   // A: 16 k-rows x 64 cols
    const int brow  = t >> 2, bk    = (t & 3) * 4;    // B: 64 rows x 16 k
    const int tx    = t & 15, ty    = t >> 4;

    const float* Ap = PT + (size_t)b * DD * NTOK + (size_t)akrow * NTOK + t0 + amcol;
    const float* Bp = B + (size_t)(bn * TBN + brow) * DD + bk;

    float4 acc[4];
    #pragma unroll
    for (int i = 0; i < 4; ++i) acc[i] = make_float4(0.f, 0.f, 0.f, 0.f);

    float4 a0 = *reinterpret_cast<const float4*>(Ap);
    float4 b0 = *reinterpret_cast<const float4*>(Bp);

    for (int k0 = 0; k0 < DD; k0 += TBK) {
        __syncthreads();
        *reinterpret_cast<float4*>(&As[akrow][amcol]) = a0;
        Bs[bk + 0][brow] = b0.x; Bs[bk + 1][brow] = b0.y;
        Bs[bk + 2][brow] = b0.z; Bs[bk + 3][brow] = b0.w;
        __syncthreads();
        if (k0 + TBK < DD) {
            a0 = *reinterpret_cast<const float4*>(Ap + (size_t)(k0 + TBK) * NTOK);
            b0 = *reinterpret_cast<const float4*>(Bp + k0 + TBK);
        }
        #pragma unroll
        for (int k = 0; k < TBK; ++k) {
            float4 av = *reinterpret_cast<const float4*>(&As[k][ty * 4]);
            float4 bv = *reinterpret_cast<const float4*>(&Bs[k][tx * 4]);
            acc[0].x = fmaf(av.x, bv.x, acc[0].x); acc[0].y = fmaf(av.x, bv.y, acc[0].y);
            acc[0].z = fmaf(av.x, bv.z, acc[0].z); acc[0].w = fmaf(av.x, bv.w, acc[0].w);
            acc[1].x = fmaf(av.y, bv.x, acc[1].x); acc[1].y = fmaf(av.y, bv.y, acc[1].y);
            acc[1].z = fmaf(av.y, bv.z, acc[1].z); acc[1].w = fmaf(av.y, bv.w, acc[1].w);
            acc[2].x = fmaf(av.z, bv.x, acc[2].x); acc[2].y = fmaf(av.z, bv.y, acc[2].y);
            acc[2].z = fmaf(av.z, bv.z, acc[2].z); acc[2].w = fmaf(av.z, bv.w, acc[2].w);
            acc[3].x = fmaf(av.w, bv.x, acc[3].x); acc[3].y = fmaf(av.w, bv.y, acc[3].y);
            acc[3].z = fmaf(av.w, bv.z, acc[3].z); acc[3].w = fmaf(av.w, bv.w, acc[3].w);
        }
    }
    #pragma unroll
    for (int i = 0; i < 4; ++i) {
        float* cp = C + (size_t)(b * NTOK + t0 + ty * 4 + i) * DD
                      + bn * TBN + tx * 4;
        *reinterpret_cast<float4*>(cp) = acc[i];
    }
}

// ---------------------------------------------------------------------------
// Gram: c_ij = h_i . h_j for j<i in chunk of 8. 1024 blocks x 128 thr (2 waves,
// split pairs by parity). XCD-swizzled: b = blk&7 warms XCD b's L2 with H_b.
// ---------------------------------------------------------------------------
__global__ __launch_bounds__(128) void gram_kernel(
    const float* __restrict__ H, float* __restrict__ Gram)
{
    const int blk  = blockIdx.x;
    const int b    = blk & 7;
    const int chk  = blk >> 3;
    const int w    = threadIdx.x >> 6;
    const int lane = threadIdx.x & 63;
    const float* Hc = H + ((size_t)b * NTOK + (size_t)chk * CH) * DD + lane * 4;

    float4 h[CH];
    #pragma unroll
    for (int i = 0; i < CH; ++i)
        h[i] = *reinterpret_cast<const float4*>(Hc + (size_t)i * DD);

    float sel = 0.f;
    #pragma unroll
    for (int i = 1; i < CH; ++i) {
        #pragma unroll
        for (int j = 0; j < i; ++j) {
            const int idx = i * (i - 1) / 2 + j;
            if ((idx & 1) == w) {
                float s = h[j].x * h[i].x;
                s = fmaf(h[j].y, h[i].y, s);
                s = fmaf(h[j].z, h[i].z, s);
                s = fmaf(h[j].w, h[i].w, s);
                REDUCE_ALL64(s);
                sel = (lane == idx) ? s : sel;
            }
        }
    }
    if (lane < 28 && (lane & 1) == w)
        Gram[((size_t)b * NCHUNK + chk) * 32 + lane] = sel;
}

// ---------------------------------------------------------------------------
// Chunked scan, XCD-swizzled (batch b -> XCD b; H_b+Tgt_b L2-resident).
// Prefetch next chunk, pinned with sched_barrier(0). Pred stored transposed.
// ---------------------------------------------------------------------------
#define GC(Cb, q) (((const float*)&(Cb)[0])[(q)])

#define STEP(HC, TC, CC, HN, TN, CN, ch) do { \
    const int nc_ = ((ch) + 1 < NCHUNK) ? (ch) + 1 : NCHUNK - 1; \
    const float* hsrc_ = Hb + (size_t)nc_ * CH * DD; \
    const float* tsrc_ = Tb + (size_t)nc_ * CH * DD; \
    const float4* gsrc_ = reinterpret_cast<const float4*>(Gb + nc_ * 32); \
    _Pragma("unroll") \
    for (int i_ = 0; i_ < CH; ++i_) { \
        HN[i_] = *reinterpret_cast<const float4*>(hsrc_ + (size_t)i_ * DD); \
        TN[i_] = LR_C * tsrc_[(size_t)i_ * DD]; \
    } \
    _Pragma("unroll") \
    for (int q_ = 0; q_ < 7; ++q_) CN[q_] = gsrc_[q_]; \
    __builtin_amdgcn_sched_barrier(0); \
    float a_[CH]; \
    _Pragma("unroll") \
    for (int i_ = 0; i_ < CH; ++i_) { \
        float s_ = HC[i_].x * th.x; \
        s_ = fmaf(HC[i_].y, th.y, s_); \
        s_ = fmaf(HC[i_].z, th.z, s_); \
        s_ = fmaf(HC[i_].w, th.w, s_); \
        REDUCE_ALL64(s_); \
        a_[i_] = s_; \
    } \
    float e_[CH], p_[CH]; \
    _Pragma("unroll") \
    for (int i_ = 0; i_ < CH; ++i_) { \
        float pv_ = a_[i_]; \
        _Pragma("unroll") \
        for (int j_ = 0; j_ < i_; ++j_) \
            pv_ = fmaf(e_[j_], GC(CC, i_ * (i_ - 1) / 2 + j_), pv_); \
        p_[i_] = pv_; \
        e_[i_] = fmaf(-LR_C, pv_, TC[i_]); \
    } \
    _Pragma("unroll") \
    for (int j_ = 0; j_ < CH; ++j_) { \
        th.x = fmaf(e_[j_], HC[j_].x, th.x); \
        th.y = fmaf(e_[j_], HC[j_].y, th.y); \
        th.z = fmaf(e_[j_], HC[j_].z, th.z); \
        th.w = fmaf(e_[j_], HC[j_].w, th.w); \
    } \
    float sel_ = p_[0]; \
    _Pragma("unroll") \
    for (int i_ = 1; i_ < CH; ++i_) sel_ = (lane == i_) ? p_[i_] : sel_; \
    if (lane < CH) Pb[(ch) * CH + lane] = sel_; \
} while (0)

__global__ __launch_bounds__(64, 2) void theta_scan_kernel(
    const float* __restrict__ H, const float* __restrict__ Tgt,
    const float* __restrict__ theta0, const float* __restrict__ Gram,
    float* __restrict__ PT)
{
    const int blk  = blockIdx.x;
    const int b    = blk & 7;            // batch -> XCD
    const int row  = blk >> 3;           // 256 rows
    const int lane = threadIdx.x;        // owns cols lane*4 .. lane*4+3

    float4 th = *reinterpret_cast<const float4*>(
        theta0 + (size_t)row * DD + lane * 4);

    const float* Hb = H    + (size_t)b * NTOK * DD + lane * 4;
    const float* Tb = Tgt  + (size_t)b * NTOK * DD + row;
    const float* Gb = Gram + (size_t)b * NCHUNK * 32;
    float*       Pb = PT   + ((size_t)b * DD + row) * NTOK;

    float4 hA[CH]; float tA[CH]; float4 cA[7];
    float4 hB[CH]; float tB[CH]; float4 cB[7];

    #pragma unroll
    for (int i = 0; i < CH; ++i) {
        hA[i] = *reinterpret_cast<const float4*>(Hb + (size_t)i * DD);
        tA[i] = LR_C * Tb[(size_t)i * DD];
    }
    #pragma unroll
    for (int q = 0; q < 7; ++q)
        cA[q] = reinterpret_cast<const float4*>(Gb)[q];

    for (int ch = 0; ch < NCHUNK; ch += 2) {
        STEP(hA, tA, cA, hB, tB, cB, ch);
        STEP(hB, tB, cB, hA, tA, cA, ch + 1);
    }
}

// ---------------------------------------------------------------------------
extern "C" void kernel_launch(void* const* d_in, const int* in_sizes, int n_in,
                              void* d_out, int out_size, void* d_ws, size_t ws_size,
                              hipStream_t stream) {
    const float* seq    = (const float*)d_in[0];
    const float* tgt    = (const float*)d_in[1];
    const float* theta0 = (const float*)d_in[2];
    const float* W_e    = (const float*)d_in[3];
    const float* W_o    = (const float*)d_in[4];
    float* out = (float*)d_out;

    float* Hbuf  = (float*)d_ws;                      // 8 MB
    float* PTbuf = Hbuf + (size_t)NB * NTOK * DD;     // 8 MB, [NB][DD][NTOK]
    // Gram scratch lives in d_out (128 KB); final GEMM overwrites all of d_out.
    float* Cbuf = out;

    dim3 ggrid(NB * NTOK / TBM, DD / TBN);            // (128, 4)

    gemm_abt_kernel<<<ggrid, 256, 0, stream>>>(seq, W_e, Hbuf);
    gram_kernel<<<NB * NCHUNK, 128, 0, stream>>>(Hbuf, Cbuf);
    theta_scan_kernel<<<NB * 256, 64, 0, stream>>>(Hbuf, tgt, theta0, Cbuf, PTbuf);
    gemm_pt_kernel<<<ggrid, 256, 0, stream>>>(PTbuf, W_o, out);
}